// Round 12
// baseline (76.305 us; speedup 1.0000x reference)
//
#include <hip/hip_runtime.h>
#include <hip/hip_bf16.h>

// BarlowTwins loss: logits[b,n,m] = sum_s z1[b,s,n]*z2[b,s,m]  (B=8, S=256, N=M=2048)
// loss = mean_{b,m}( LSE_n(logits[b,:,m]) - logits[b,m,m] )
//
// Round-12 = R11 (30.1us: 512m x 256n blocks, wave owns 64m x full 256n, reg-staged
// f32->bf16->LDS stride-264 dbuf, 1 barrier/tile, exp2-sum, no max tracking)
// + T15 double-accumulator exp-deferral: tile t's 32 MFMAs interleave with tile t-1's
// 32 exp2+adds (even/odd acc name pairs, ALL indices compile-time). MFMA and VALU/TRANS
// are separate pipes (m114) -> exp leaves the per-tile critical path. Diag deferred too.
// R7's version of this spilled because __launch_bounds__(512,2) capped VGPR at 128;
// here launch_bounds(512) + lean apf (16 regs) puts live set ~230 < 256.

#define NN 2048
#define SK 256
#define LDST 264
#define LOG2E 1.4426950408889634f
#define LN2   0.6931471805599453f
#define COFF  96.0f

typedef __attribute__((ext_vector_type(8))) short short8;
typedef __attribute__((ext_vector_type(16))) float f32x16;

__device__ __forceinline__ unsigned short f2bf(float f) {
    __hip_bfloat16 h = __float2bfloat16(f);
    unsigned short u; __builtin_memcpy(&u, &h, 2); return u;
}

__device__ __forceinline__ float exp2g(float x) {
#if __has_builtin(__builtin_amdgcn_exp2f)
    return __builtin_amdgcn_exp2f(x);
#else
    return exp2f(x);
#endif
}

__device__ __forceinline__ float log2g(float x) {
#if __has_builtin(__builtin_amdgcn_logf)
    return __builtin_amdgcn_logf(x);
#else
    return log2f(x);
#endif
}

__global__ __launch_bounds__(512) void gemm_lse_kernel(
    const float* __restrict__ z1, const float* __restrict__ z2,
    float* __restrict__ ws_sum, float* __restrict__ ws_diag)
{
    __shared__ unsigned short lds[2][32 * LDST];   // 2 x 16.9 KB

    const int bid  = blockIdx.x;
    const int b    = bid & 7;          // XCD-aligned batch
    const int tile = bid >> 3;
    const int mb   = tile & 3;         // 4 m-blocks of 512
    const int ns   = tile >> 2;        // 8 n-splits of 256
    const int tid  = threadIdx.x;
    const int lane = tid & 63;
    const int w    = tid >> 6;         // wave 0..7 owns 64 m
    const int col  = lane & 31;
    const int kg   = lane >> 5;

    const int m0      = mb * 512 + w * 64;   // strip0; strip1 = +32
    const int mcol0   = m0 + col;
    const int mcol1   = m0 + 32 + col;
    const int n_start = ns * 256;

    const float* z1b = z1 + (size_t)b * SK * NN;
    const float* z2b = z2 + (size_t)b * SK * NN;

    // ---- A staging: tile = 32 n-rows x 256 k; thread (kc,row) loads 16 f32 ----
    const int kc  = (w << 1) | kg;     // k-chunk 0..15 (16 s each)
    const int row = col;               // n-row 0..31
    float apf[16];
    auto load_A = [&](int t) {
        const float* p = z1b + (size_t)(kc * 16) * NN + (n_start + 32 * t + row);
        #pragma unroll
        for (int j = 0; j < 16; ++j) apf[j] = p[(size_t)j * NN];
    };
    auto store_A = [&](unsigned short* buf) {
        short8 pk0, pk1;
        #pragma unroll
        for (int j = 0; j < 8; ++j) { pk0[j] = (short)f2bf(apf[j]); pk1[j] = (short)f2bf(apf[j + 8]); }
        *(short8*)(buf + row * LDST + kc * 16)     = pk0;
        *(short8*)(buf + row * LDST + kc * 16 + 8) = pk1;
    };

    // ---- prologue: B K-half 0, stage tiles 0/1, B K-half 1 (latency overlap) ----
    short8 bf0[16], bf1[16];
    auto loadB = [&](int ks) {
        short8 p0, p1;
        #pragma unroll
        for (int j = 0; j < 8; ++j) {
            const int s = ks * 16 + kg * 8 + j;
            p0[j] = (short)f2bf(z2b[(size_t)s * NN + mcol0] * LOG2E);
            p1[j] = (short)f2bf(z2b[(size_t)s * NN + mcol1] * LOG2E);
        }
        bf0[ks] = p0; bf1[ks] = p1;
    };

    #pragma unroll
    for (int ks = 0; ks < 8; ++ks) loadB(ks);
    load_A(0);
    store_A(lds[0]);
    load_A(1);
    #pragma unroll
    for (int ks = 8; ks < 16; ++ks) loadB(ks);

    float srun0 = 0.0f, srun1 = 0.0f;
    f32x16 accE0, accE1, accO0, accO1;

    __syncthreads();   // buf0 visible

// Tile T: MFMA into CUR while exp2-summing PREVIOUS tile's PRV (interleaved, static
// indices; MFMA & VALU/TRANS are separate pipes). Diag deferred: captured from PRV.
#define TILE_BODY(T, CUR0, CUR1, PRV0, PRV1, DOP)                                    \
    {                                                                                \
        const unsigned short* abase = lds[(T) & 1] + col * LDST + kg * 8;            \
        _Pragma("unroll")                                                            \
        for (int r = 0; r < 16; ++r) { CUR0[r] = -COFF; CUR1[r] = -COFF; }           \
        float f0 = 0, f1 = 0, g0 = 0, g1 = 0;                                        \
        _Pragma("unroll")                                                            \
        for (int ks = 0; ks < 16; ++ks) {                                            \
            short8 af = *(const short8*)(abase + ks * 16);                           \
            CUR0 = __builtin_amdgcn_mfma_f32_32x32x16_bf16(af, bf0[ks], CUR0, 0, 0, 0); \
            CUR1 = __builtin_amdgcn_mfma_f32_32x32x16_bf16(af, bf1[ks], CUR1, 0, 0, 0); \
            if (DOP) {                                                               \
                if (ks & 1) { f1 += exp2g(PRV0[ks]); g1 += exp2g(PRV1[ks]); }        \
                else        { f0 += exp2g(PRV0[ks]); g0 += exp2g(PRV1[ks]); }        \
            }                                                                        \
        }                                                                            \
        if (DOP) { srun0 += f0 + f1; srun1 += g0 + g1; }                             \
        if (DOP) {                                                                   \
            const int nsubP = n_start + 32 * ((T) - 1);                              \
            if (nsubP == m0) {                                                       \
                _Pragma("unroll")                                                    \
                for (int r = 0; r < 16; ++r) {                                       \
                    const int rw = (r & 3) + 8 * (r >> 2) + 4 * kg;                  \
                    if (rw == col) ws_diag[b * NN + mcol0] = PRV0[r];                \
                }                                                                    \
            }                                                                        \
            if (nsubP == m0 + 32) {                                                  \
                _Pragma("unroll")                                                    \
                for (int r = 0; r < 16; ++r) {                                       \
                    const int rw = (r & 3) + 8 * (r >> 2) + 4 * kg;                  \
                    if (rw == col) ws_diag[b * NN + mcol1] = PRV1[r];                \
                }                                                                    \
            }                                                                        \
        }                                                                            \
        if ((T) < 7) store_A(lds[((T) + 1) & 1]);                                    \
        if ((T) < 6) load_A((T) + 2);                                                \
        __syncthreads();                                                             \
    }

    TILE_BODY(0, accE0, accE1, accO0, accO1, false)
    TILE_BODY(1, accO0, accO1, accE0, accE1, true)
    TILE_BODY(2, accE0, accE1, accO0, accO1, true)
    TILE_BODY(3, accO0, accO1, accE0, accE1, true)
    TILE_BODY(4, accE0, accE1, accO0, accO1, true)
    TILE_BODY(5, accO0, accO1, accE0, accE1, true)
    TILE_BODY(6, accE0, accE1, accO0, accO1, true)
    TILE_BODY(7, accO0, accO1, accE0, accE1, true)
#undef TILE_BODY

    // tail: exp2-sum + diag for tile 7 (lives in accO pair)
    {
        float f0 = 0, f1 = 0, g0 = 0, g1 = 0;
        #pragma unroll
        for (int r = 0; r < 16; r += 2) {
            f0 += exp2g(accO0[r]); f1 += exp2g(accO0[r + 1]);
            g0 += exp2g(accO1[r]); g1 += exp2g(accO1[r + 1]);
        }
        srun0 += f0 + f1; srun1 += g0 + g1;

        const int nsubP = n_start + 32 * 7;
        if (nsubP == m0) {
            #pragma unroll
            for (int r = 0; r < 16; ++r) {
                const int rw = (r & 3) + 8 * (r >> 2) + 4 * kg;
                if (rw == col) ws_diag[b * NN + mcol0] = accO0[r];
            }
        }
        if (nsubP == m0 + 32) {
            #pragma unroll
            for (int r = 0; r < 16; ++r) {
                const int rw = (r & 3) + 8 * (r >> 2) + 4 * kg;
                if (rw == col) ws_diag[b * NN + mcol1] = accO1[r];
            }
        }
    }

    // combine kg halves; one writer per m-col (wave owns its cols exclusively)
    srun0 += __shfl_xor(srun0, 32);
    srun1 += __shfl_xor(srun1, 32);
    if (kg == 0) {
        ws_sum[(b * 8 + ns) * NN + mcol0] = srun0;
        ws_sum[(b * 8 + ns) * NN + mcol1] = srun1;
    }
}

__global__ __launch_bounds__(256) void merge_kernel(
    const float* __restrict__ ws_sum, const float* __restrict__ ws_diag,
    float* __restrict__ partial)
{
    const int gid = blockIdx.x * 256 + threadIdx.x;   // 0..16383
    const int b = gid >> 11, m = gid & (NN - 1);

    float S = 0.0f;
    #pragma unroll
    for (int slot = 0; slot < 8; ++slot)
        S += ws_sum[(b * 8 + slot) * NN + m];
    float c = log2g(S) - ws_diag[gid];   // (LSE' - diag') in log2 units

    #pragma unroll
    for (int d = 1; d < 64; d <<= 1) c += __shfl_xor(c, d);
    __shared__ float red[4];
    if ((threadIdx.x & 63) == 0) red[threadIdx.x >> 6] = c;
    __syncthreads();
    if (threadIdx.x == 0)
        partial[blockIdx.x] = red[0] + red[1] + red[2] + red[3];
}

__global__ void final_kernel(const float* __restrict__ partial, float* __restrict__ out)
{
    float v = partial[threadIdx.x];   // 64 threads
    #pragma unroll
    for (int d = 1; d < 64; d <<= 1) v += __shfl_xor(v, d);
    if (threadIdx.x == 0) out[0] = v * (LN2 / 16384.0f);
}

extern "C" void kernel_launch(void* const* d_in, const int* in_sizes, int n_in,
                              void* d_out, int out_size, void* d_ws, size_t ws_size,
                              hipStream_t stream)
{
    const float* z1 = (const float*)d_in[0];
    const float* z2 = (const float*)d_in[1];
    float* ws  = (float*)d_ws;
    float* out = (float*)d_out;

    // ws layout (floats): sum[8][8][2048] | diag[8][2048] | partial[64]
    float* ws_sum  = ws;
    float* ws_diag = ws + 131072;
    float* ws_part = ws + 147456;

    gemm_lse_kernel<<<dim3(256), dim3(512), 0, stream>>>(z1, z2, ws_sum, ws_diag);
    merge_kernel<<<dim3(64), dim3(256), 0, stream>>>(ws_sum, ws_diag, ws_part);
    final_kernel<<<dim3(1), dim3(64), 0, stream>>>(ws_part, out);
}

// Round 13
// 36.031 us; speedup vs baseline: 2.1178x; 2.1178x over previous
//
#include <hip/hip_runtime.h>
#include <hip/hip_bf16.h>

// BarlowTwins loss: logits[b,n,m] = sum_s z1[b,s,n]*z2[b,s,m]  (B=8, S=256, N=M=2048)
// loss = mean_{b,m}( LSE_n(logits[b,:,m]) - logits[b,m,m] )
//
// Round-13: fit in the compiler's hard 128-VGPR choice (R7/R12 evidence: 512-thr kernels
// get 128 arch VGPRs, period; 2-strip B-frags = 128 VGPR alone -> chronic spill).
//  - Wave owns ONE 32-m strip: bf[16] = 64 VGPR. B-reuse recovered by computing TWO
//    32-n subtiles per 64-n tile with the same bf (32 MFMA : 32 ds_read).
//  - Block = 256m x 512n, grid 256 = 8b x 8mb x 4ns, 1/CU lockstep (L2-validated).
//  - A: K1 transposes z1 -> bf16 K-major z1t (R10-verified); gemm stages via
//    global_load_lds + both-sides XOR swizzle (R8-verified), 3 bufs, counted vmcnt.
//    Zero staging VGPRs, zero cvt in the gemm.
//  - acc init -96 with z2 pre-scaled by log2e at the B-prologue cvt; exp2-sum, no max
//    tracking (headroom ~2^33, validated since R2). accs live in AGPRs.
//  K3/K4: merge 4 n-partials (log2 S - diag; offset cancels) + mean * ln2.

#define NN 2048
#define SK 256
#define LOG2E 1.4426950408889634f
#define LN2   0.6931471805599453f
#define COFF  96.0f
#define TILE_ELEMS (64 * SK)   // 64 rows x 512B = 32 KB

typedef __attribute__((ext_vector_type(8))) short short8;
typedef __attribute__((ext_vector_type(16))) float f32x16;

__device__ __forceinline__ unsigned short f2bf(float f) {
    __hip_bfloat16 h = __float2bfloat16(f);
    unsigned short u; __builtin_memcpy(&u, &h, 2); return u;
}

__device__ __forceinline__ float exp2g(float x) {
#if __has_builtin(__builtin_amdgcn_exp2f)
    return __builtin_amdgcn_exp2f(x);
#else
    return exp2f(x);
#endif
}

__device__ __forceinline__ float log2g(float x) {
#if __has_builtin(__builtin_amdgcn_logf)
    return __builtin_amdgcn_logf(x);
#else
    return log2f(x);
#endif
}

__device__ __forceinline__ void gload16(const unsigned short* g, unsigned short* l) {
    // async global->LDS, 16B x 64 lanes; LDS dest = wave-uniform base + lane*16
    __builtin_amdgcn_global_load_lds(
        (const __attribute__((address_space(1))) unsigned int*)(g),
        (__attribute__((address_space(3))) unsigned int*)(l),
        16, 0, 0);
}

// ---------------- K1: transpose + cvt prepass, z1 only (R10-verified) ----------------
__global__ __launch_bounds__(256) void transpose_kernel(
    const float* __restrict__ z1, unsigned short* __restrict__ z1t)
{
    __shared__ float lds[64][65];

    const int bid = blockIdx.x;         // 1024 blocks
    const int b   = bid >> 7;
    const int st  = (bid >> 5) & 3;     // s-tile (4 x 64)
    const int nt  = bid & 31;           // n-tile (32 x 64)

    const float* in = z1 + (size_t)b * SK * NN + (size_t)(st * 64) * NN + nt * 64;
    unsigned short* out = z1t + (size_t)b * NN * SK + (size_t)(nt * 64) * SK + st * 64;

    const int tid = threadIdx.x;
    const int n4 = tid & 15, sl = tid >> 4;
    #pragma unroll
    for (int r = 0; r < 4; ++r) {
        const int s = r * 16 + sl;
        float4 v = *(const float4*)(in + (size_t)s * NN + n4 * 4);
        lds[n4 * 4 + 0][s] = v.x;
        lds[n4 * 4 + 1][s] = v.y;
        lds[n4 * 4 + 2][s] = v.z;
        lds[n4 * 4 + 3][s] = v.w;
    }
    __syncthreads();

    const int nr = tid >> 2, q = tid & 3;
    short8 o0, o1;
    #pragma unroll
    for (int i = 0; i < 8; ++i) o0[i] = (short)f2bf(lds[nr][q * 16 + i]);
    #pragma unroll
    for (int i = 0; i < 8; ++i) o1[i] = (short)f2bf(lds[nr][q * 16 + 8 + i]);
    *(short8*)(out + (size_t)nr * SK + q * 16)     = o0;
    *(short8*)(out + (size_t)nr * SK + q * 16 + 8) = o1;
}

// ---------------- K2: fused GEMM + exp2-sum, 1-strip / 2-subtile ----------------
__global__ __launch_bounds__(512) void gemm_lse_kernel(
    const unsigned short* __restrict__ z1t, const float* __restrict__ z2,
    float* __restrict__ ws_sum, float* __restrict__ ws_diag)
{
    __shared__ unsigned short ldsA[3 * TILE_ELEMS];   // 96 KB

    const int bid  = blockIdx.x;
    const int b    = bid & 7;          // XCD-aligned batch
    const int tile = bid >> 3;
    const int mb   = tile & 7;         // 8 m-blocks of 256
    const int ns   = tile >> 3;        // 4 n-splits of 512
    const int tid  = threadIdx.x;
    const int lane = tid & 63;
    const int w    = tid >> 6;         // wave 0..7: one 32-m strip each
    const int col  = lane & 31;
    const int kg   = lane >> 5;

    const int mstrip  = mb * 256 + w * 32;
    const int mcol    = mstrip + col;
    const int n_start = ns * 512;

    const unsigned short* z1b = z1t + (size_t)b * NN * SK;
    const float*          z2b = z2  + (size_t)b * SK * NN;

    // ---- async A staging: tile t = 64 rows x 512B; wave w stages rows 8w..8w+7 ----
    auto stage = [&](int t, int bufi) {
        unsigned short* buf = &ldsA[bufi * TILE_ELEMS];
        const unsigned short* src = z1b + (size_t)(n_start + 64 * t) * SK;
        #pragma unroll
        for (int q = 0; q < 4; ++q) {
            const int r0    = 8 * w + 2 * q;            // wave-uniform row pair
            const int row   = r0 + (lane >> 5);
            const int off16 = (lane & 31) ^ (row & 31); // pre-swizzled source slot
            gload16(src + (size_t)row * SK + off16 * 8, buf + (size_t)r0 * SK);
        }
    };

    stage(0, 0);
    stage(1, 1);

    // ---- B fragments: ONE strip, coalesced f32 column loads, x log2e ----
    short8 bf[16];
    #pragma unroll
    for (int ks = 0; ks < 16; ++ks) {
        short8 pk;
        #pragma unroll
        for (int j = 0; j < 8; ++j) {
            const int s = ks * 16 + kg * 8 + j;
            pk[j] = (short)f2bf(z2b[(size_t)s * NN + mcol] * LOG2E);
        }
        bf[ks] = pk;
    }

    float srun = 0.0f;

    asm volatile("s_waitcnt vmcnt(0)" ::: "memory");   // buf0/buf1 + B landed
    __syncthreads();

    for (int t = 0; t < 8; ++t) {
        if (t < 6) stage(t + 2, (t + 2) % 3);   // async, overlaps compute

        const unsigned short* base = &ldsA[(t % 3) * TILE_ELEMS];
        const unsigned short* a0 = base + (size_t)col * SK;         // subtile 0 rows
        const unsigned short* a1 = base + (size_t)(32 + col) * SK;  // subtile 1 rows
        // xr = rowi & 31 == col for both subtiles

        f32x16 acc0, acc1;
        #pragma unroll
        for (int r = 0; r < 16; ++r) { acc0[r] = -COFF; acc1[r] = -COFF; }

        __builtin_amdgcn_s_setprio(1);
        #pragma unroll
        for (int ks = 0; ks < 16; ++ks) {
            const int so = ((((ks << 1) | kg) ^ col) << 3);   // swizzled 16B slot
            short8 af0 = *(const short8*)(a0 + so);
            short8 af1 = *(const short8*)(a1 + so);
            acc0 = __builtin_amdgcn_mfma_f32_32x32x16_bf16(af0, bf[ks], acc0, 0, 0, 0);
            acc1 = __builtin_amdgcn_mfma_f32_32x32x16_bf16(af1, bf[ks], acc1, 0, 0, 0);
        }
        __builtin_amdgcn_s_setprio(0);

        // diagonal capture (acc = logit' - 96; offset cancels in merge)
        const int nsub0 = n_start + 64 * t;
        if (nsub0 == mstrip) {
            #pragma unroll
            for (int r = 0; r < 16; ++r) {
                const int rw = (r & 3) + 8 * (r >> 2) + 4 * kg;
                if (rw == col) ws_diag[b * NN + mcol] = acc0[r];
            }
        }
        if (nsub0 + 32 == mstrip) {
            #pragma unroll
            for (int r = 0; r < 16; ++r) {
                const int rw = (r & 3) + 8 * (r >> 2) + 4 * kg;
                if (rw == col) ws_diag[b * NN + mcol] = acc1[r];
            }
        }

        // exp2-sum, 4 independent chains across both subtiles
        {
            float e0 = 0, e1 = 0, e2 = 0, e3 = 0;
            #pragma unroll
            for (int r = 0; r < 16; r += 4) {
                e0 += exp2g(acc0[r]);     e1 += exp2g(acc0[r + 1]);
                e2 += exp2g(acc0[r + 2]); e3 += exp2g(acc0[r + 3]);
            }
            #pragma unroll
            for (int r = 0; r < 16; r += 4) {
                e0 += exp2g(acc1[r]);     e1 += exp2g(acc1[r + 1]);
                e2 += exp2g(acc1[r + 2]); e3 += exp2g(acc1[r + 3]);
            }
            srun += (e0 + e1) + (e2 + e3);
        }

        // counted end-of-tile wait (R10 pattern): keep tile-after's loads in flight
        if (t < 6) {
            asm volatile("s_waitcnt vmcnt(4)" ::: "memory");
            __builtin_amdgcn_s_barrier();
            __builtin_amdgcn_sched_barrier(0);
        } else if (t == 6) {
            asm volatile("s_waitcnt vmcnt(0)" ::: "memory");
            __builtin_amdgcn_s_barrier();
            __builtin_amdgcn_sched_barrier(0);
        }
    }

    srun += __shfl_xor(srun, 32);
    if (kg == 0) {
        ws_sum[(b * 4 + ns) * NN + mcol] = srun;   // 4 n-partials per (b,m)
    }
}

// ---------------- K3/K4: merge + reduce ----------------
__global__ __launch_bounds__(256) void merge_kernel(
    const float* __restrict__ ws_sum, const float* __restrict__ ws_diag,
    float* __restrict__ partial)
{
    const int gid = blockIdx.x * 256 + threadIdx.x;   // 0..16383
    const int b = gid >> 11, m = gid & (NN - 1);

    float S = 0.0f;
    #pragma unroll
    for (int slot = 0; slot < 4; ++slot)
        S += ws_sum[(b * 4 + slot) * NN + m];
    float c = log2g(S) - ws_diag[gid];   // (LSE' - diag') in log2 units

    #pragma unroll
    for (int d = 1; d < 64; d <<= 1) c += __shfl_xor(c, d);
    __shared__ float red[4];
    if ((threadIdx.x & 63) == 0) red[threadIdx.x >> 6] = c;
    __syncthreads();
    if (threadIdx.x == 0)
        partial[blockIdx.x] = red[0] + red[1] + red[2] + red[3];
}

__global__ void final_kernel(const float* __restrict__ partial, float* __restrict__ out)
{
    float v = partial[threadIdx.x];   // 64 threads
    #pragma unroll
    for (int d = 1; d < 64; d <<= 1) v += __shfl_xor(v, d);
    if (threadIdx.x == 0) out[0] = v * (LN2 / 16384.0f);
}

extern "C" void kernel_launch(void* const* d_in, const int* in_sizes, int n_in,
                              void* d_out, int out_size, void* d_ws, size_t ws_size,
                              hipStream_t stream)
{
    const float* z1 = (const float*)d_in[0];
    const float* z2 = (const float*)d_in[1];
    float* out = (float*)d_out;

    // ws: z1t bf16 [8][2048][256] (8MB) | sum f32 [8][4][2048] | diag [8][2048] | partial[64]
    char* wsb = (char*)d_ws;
    unsigned short* z1t = (unsigned short*)wsb;
    float* ws_sum  = (float*)(wsb + (8u << 20));
    float* ws_diag = ws_sum + 8 * 4 * NN;
    float* ws_part = ws_diag + 8 * NN;

    transpose_kernel<<<dim3(1024), dim3(256), 0, stream>>>(z1, z1t);
    gemm_lse_kernel<<<dim3(256), dim3(512), 0, stream>>>(z1t, z2, ws_sum, ws_diag);
    merge_kernel<<<dim3(64), dim3(256), 0, stream>>>(ws_sum, ws_diag, ws_part);
    final_kernel<<<dim3(1), dim3(64), 0, stream>>>(ws_part, out);
}